// Round 1
// baseline (911.395 us; speedup 1.0000x reference)
//
#include <hip/hip_runtime.h>
#include <hip/hip_bf16.h>
#include <stdint.h>

// Bayesian MHA forward for MI355X.
// B=8, N=1024, D=1024, H=16, dk=64, d_raw=16.
// Mean path uses split-bf16 (hi/lo, 3-MFMA) => ~fp32 accuracy.
// PV uses f16 MFMA; variance path plain bf16.

#define D_MODEL 1024
#define NSEQ    1024
#define BATCH   8
#define NHEADS  16
#define DK      64
#define TOK     8192   // BATCH*NSEQ

typedef __bf16    bf8 __attribute__((ext_vector_type(8)));
typedef _Float16  h8  __attribute__((ext_vector_type(8)));
typedef float     f4  __attribute__((ext_vector_type(4)));

__device__ __forceinline__ f4 mfma_bf(bf8 a, bf8 b, f4 c){
  return __builtin_amdgcn_mfma_f32_16x16x32_bf16(a, b, c, 0, 0, 0);
}
__device__ __forceinline__ f4 mfma_h(h8 a, h8 b, f4 c){
  return __builtin_amdgcn_mfma_f32_16x16x32_f16(a, b, c, 0, 0, 0);
}

// global -> LDS async copy, 16B per lane. LDS dest must be (uniform base + lane*16).
__device__ __forceinline__ void async_copy16(void* lds, const void* g){
  __builtin_amdgcn_global_load_lds(
      (const __attribute__((address_space(1))) unsigned int*)(uintptr_t)g,
      (__attribute__((address_space(3))) unsigned int*)(unsigned int)(uintptr_t)lds,
      16, 0, 0);
}

__device__ __forceinline__ float softplusf(float x){
  return (x > 20.f) ? x : log1pf(__expf(x));
}

// ---------------- prep kernels ----------------

// f32 -> bf16 hi/lo split (hi = bf16(x), lo = bf16(x - hi))
__global__ __launch_bounds__(256) void split_f32_bf16(
    const float* __restrict__ in, __bf16* __restrict__ hi, __bf16* __restrict__ lo, int n){
  int i = (blockIdx.x*256 + threadIdx.x)*4;
  if (i >= n) return;
  float4 v = *(const float4*)(in + i);
  float vv[4] = {v.x, v.y, v.z, v.w};
  #pragma unroll
  for (int j=0;j<4;j++){
    __bf16 h = (__bf16)vv[j];
    hi[i+j] = h;
    lo[i+j] = (__bf16)(vv[j] - (float)h);
  }
}

// mode 0: out = bf16(x*x);  mode 1: out = bf16(softplus(x)^2)
__global__ __launch_bounds__(256) void sq_to_bf16(
    const float* __restrict__ in, __bf16* __restrict__ out, int n, int mode){
  int i = (blockIdx.x*256 + threadIdx.x)*4;
  if (i >= n) return;
  float4 v = *(const float4*)(in + i);
  float vv[4] = {v.x, v.y, v.z, v.w};
  #pragma unroll
  for (int j=0;j<4;j++){
    float f = vv[j];
    if (mode){ float s = softplusf(f); f = s*s; } else { f = f*f; }
    out[i+j] = (__bf16)f;
  }
}

// x2[t] = sum_{j<16} x_raw[t][j]^2
__global__ __launch_bounds__(256) void x2_kernel(
    const float* __restrict__ x, float* __restrict__ out, int T){
  int t = blockIdx.x*256 + threadIdx.x;
  if (t >= T) return;
  const float* p = x + (size_t)t*16;
  float s = 0.f;
  #pragma unroll
  for (int j=0;j<16;j++) s += p[j]*p[j];
  out[t] = s;
}

// ---------------- GEMM: C = A @ B^T (+bias), A:[M,K], B:[N,K] both K-contiguous ----------------
// 128x128 tile, BK=32, 4 waves (2x2, each 64x64). LDS chunks XOR-swizzled (2-bit).
// SPLIT: A/B given as hi/lo pairs, 3 MFMAs per fragment pair (~fp32 accuracy).
// Outputs (any subset): outF f32, outHi/outLo bf16 split, outT transposed f16
//   outT[b*1M + col*1024 + (row&1023)]  (row = b*1024 + n).
template<bool SPLIT>
__global__ __launch_bounds__(256) void gemm_bt(
    const __bf16* __restrict__ Ahi, const __bf16* __restrict__ Alo,
    const __bf16* __restrict__ Bhi, const __bf16* __restrict__ Blo,
    int M, int N, int K,
    const float* __restrict__ bias, int bias_sp2,
    const float* __restrict__ addend,
    float* __restrict__ outF,
    __bf16* __restrict__ outHi, __bf16* __restrict__ outLo,
    _Float16* __restrict__ outT)
{
  __shared__ __bf16 sA[(SPLIT?2:1)*128*32];
  __shared__ __bf16 sB[(SPLIT?2:1)*128*32];
  const int tid = threadIdx.x;
  const int lane = tid & 63;
  const int wid  = tid >> 6;
  const int wm = wid >> 1, wn = wid & 1;
  const int l15 = lane & 15, l4 = lane >> 4;
  const int nbn = N >> 7;
  const int bm = blockIdx.x / nbn, bn = blockIdx.x % nbn;
  const int row0 = bm << 7, col0 = bn << 7;

  f4 acc[4][4];
  #pragma unroll
  for (int i=0;i<4;i++)
    #pragma unroll
    for (int j=0;j<4;j++)
      #pragma unroll
      for (int r=0;r<4;r++) acc[i][j][r] = 0.f;

  // staging: 512 chunks (16B) per 8KB tile, 2 per thread; pre-swizzled global src
  const int c0 = tid, c1 = tid + 256;
  const int r0 = c0 >> 2, ch0 = c0 & 3;
  const int r1 = c1 >> 2, ch1 = c1 & 3;
  const int k0off = ((ch0 ^ (r0 & 3)) << 3);
  const int k1off = ((ch1 ^ (r1 & 3)) << 3);

  for (int kt = 0; kt < K; kt += 32){
    __syncthreads();
    async_copy16(&sA[c0*8], Ahi + (size_t)(row0+r0)*K + kt + k0off);
    async_copy16(&sA[c1*8], Ahi + (size_t)(row0+r1)*K + kt + k1off);
    async_copy16(&sB[c0*8], Bhi + (size_t)(col0+r0)*K + kt + k0off);
    async_copy16(&sB[c1*8], Bhi + (size_t)(col0+r1)*K + kt + k1off);
    if (SPLIT){
      async_copy16(&sA[4096 + c0*8], Alo + (size_t)(row0+r0)*K + kt + k0off);
      async_copy16(&sA[4096 + c1*8], Alo + (size_t)(row0+r1)*K + kt + k1off);
      async_copy16(&sB[4096 + c0*8], Blo + (size_t)(col0+r0)*K + kt + k0off);
      async_copy16(&sB[4096 + c1*8], Blo + (size_t)(col0+r1)*K + kt + k1off);
    }
    __syncthreads();

    bf8 a0[4], a1[4], b0[4], b1[4];
    #pragma unroll
    for (int mf=0; mf<4; mf++){
      int r  = (wm<<6) + (mf<<4) + l15;
      int ck = l4 ^ (r & 3);
      a0[mf] = *(const bf8*)&sA[r*32 + ck*8];
      if (SPLIT) a1[mf] = *(const bf8*)&sA[4096 + r*32 + ck*8];
    }
    #pragma unroll
    for (int nf=0; nf<4; nf++){
      int r  = (wn<<6) + (nf<<4) + l15;
      int ck = l4 ^ (r & 3);
      b0[nf] = *(const bf8*)&sB[r*32 + ck*8];
      if (SPLIT) b1[nf] = *(const bf8*)&sB[4096 + r*32 + ck*8];
    }
    #pragma unroll
    for (int mf=0; mf<4; mf++)
      #pragma unroll
      for (int nf=0; nf<4; nf++){
        acc[mf][nf] = mfma_bf(a0[mf], b0[nf], acc[mf][nf]);
        if (SPLIT){
          acc[mf][nf] = mfma_bf(a0[mf], b1[nf], acc[mf][nf]);
          acc[mf][nf] = mfma_bf(a1[mf], b0[nf], acc[mf][nf]);
        }
      }
  }

  // epilogue: C row = (l4*4 + r), col = l15 within each 16x16 fragment
  #pragma unroll
  for (int nf=0; nf<4; nf++){
    int col = col0 + (wn<<6) + (nf<<4) + l15;
    float bv = 0.f;
    if (bias){
      float bb = bias[col];
      if (bias_sp2){ float s = softplusf(bb); bv = s*s; } else bv = bb;
    }
    #pragma unroll
    for (int mf=0; mf<4; mf++){
      int rbase = row0 + (wm<<6) + (mf<<4) + (l4<<2);
      #pragma unroll
      for (int r=0;r<4;r++){
        int row = rbase + r;
        size_t idx = (size_t)row*N + col;
        float v = acc[mf][nf][r] + bv;
        if (addend) v += addend[idx];
        if (outF)  outF[idx] = v;
        if (outHi){
          __bf16 hh = (__bf16)v;
          outHi[idx] = hh;
          outLo[idx] = (__bf16)(v - (float)hh);
        }
        if (outT) outT[((size_t)(row>>10)<<20) + ((size_t)col<<10) + (row & 1023)] = (_Float16)v;
      }
    }
  }
}

// ---------------- fused attention (flash-style, + RBF scores) ----------------
// grid: 1024 blocks = 8 q-tiles x (B*H). 256 thr = 4 waves, each wave owns 32 q-rows.
__global__ __launch_bounds__(256) void attn_kernel(
    const __bf16* __restrict__ Qhi, const __bf16* __restrict__ Qlo,
    const __bf16* __restrict__ Khi, const __bf16* __restrict__ Klo,
    const _Float16* __restrict__ Vt, const _Float16* __restrict__ Vvt,
    const __bf16* __restrict__ xhi, const __bf16* __restrict__ xlo,
    const float* __restrict__ x2g,
    const float* __restrict__ log_sigma_f, const float* __restrict__ log_length,
    float* __restrict__ ctx_out, float* __restrict__ var_out)
{
  const int qt = blockIdx.x & 7;
  const int bh = blockIdx.x >> 3;
  const int b  = bh >> 4, h = bh & 15;
  const int lane = threadIdx.x & 63, wid = threadIdx.x >> 6;
  const int l15 = lane & 15, l4 = lane >> 4;
  const float sig2   = __expf(2.f*log_sigma_f[h]);
  const float inv2l2 = 0.5f*__expf(-2.f*log_length[h]);

  __shared__ __bf16   sKhi[64*64];
  __shared__ __bf16   sKlo[64*64];
  __shared__ _Float16 sVt[64*64];   // [d][m]
  __shared__ _Float16 sVvt[64*64];
  __shared__ _Float16 sP[128*64];   // [q][m], per-wave slices, swizzled

  const int t0 = b*NSEQ + qt*128;
  const int wq = wid*32;

  // Q fragments (hi/lo), held in regs for the whole block
  bf8 qh[2][2], ql[2][2];
  #pragma unroll
  for (int fq=0; fq<2; fq++)
    #pragma unroll
    for (int ks=0; ks<2; ks++){
      size_t off = (size_t)(t0 + wq + fq*16 + l15)*D_MODEL + h*DK + ks*32 + l4*8;
      qh[fq][ks] = *(const bf8*)(Qhi + off);
      ql[fq][ks] = *(const bf8*)(Qlo + off);
    }
  // x_raw q fragments (K=16 zero-padded to 32)
  bf8 xqh[2], xql[2];
  #pragma unroll
  for (int fq=0; fq<2; fq++){
    if (l4 < 2){
      size_t off = (size_t)(t0 + wq + fq*16 + l15)*16 + l4*8;
      xqh[fq] = *(const bf8*)(xhi + off);
      xql[fq] = *(const bf8*)(xlo + off);
    } else {
      #pragma unroll
      for (int j=0;j<8;j++){ xqh[fq][j] = (__bf16)0.f; xql[fq][j] = (__bf16)0.f; }
    }
  }
  // x2 for this wave's q-rows (C-fragment row mapping l4*4+r)
  float x2q[2][4];
  #pragma unroll
  for (int fq=0; fq<2; fq++)
    #pragma unroll
    for (int r=0;r<4;r++) x2q[fq][r] = x2g[t0 + wq + fq*16 + l4*4 + r];

  f4 mrun[2], lrun[2], ctx[2][4], var[2][4];
  #pragma unroll
  for (int fq=0; fq<2; fq++){
    #pragma unroll
    for (int r=0;r<4;r++){ mrun[fq][r] = -1e30f; lrun[fq][r] = 0.f; }
    #pragma unroll
    for (int fd=0; fd<4; fd++)
      #pragma unroll
      for (int r=0;r<4;r++){ ctx[fq][fd][r] = 0.f; var[fq][fd][r] = 0.f; }
  }

  for (int mt=0; mt<NSEQ; mt+=64){
    __syncthreads();
    // stage K(hi/lo) [m][d] and Vt/Vvt [d][m], XOR-swizzled via pre-swizzled source
    #pragma unroll
    for (int cc=0; cc<2; cc++){
      int c  = threadIdx.x + cc*256;
      int rg = c >> 3, ch = c & 7;
      int sw = (ch ^ (rg & 7)) << 3;
      size_t koff = (size_t)(b*NSEQ + mt + rg)*D_MODEL + h*DK + sw;
      async_copy16(&sKhi[c*8], Khi + koff);
      async_copy16(&sKlo[c*8], Klo + koff);
      size_t voff = ((size_t)b << 20) + (size_t)(h*DK + rg)*NSEQ + mt + sw;
      async_copy16(&sVt[c*8],  Vt  + voff);
      async_copy16(&sVvt[c*8], Vvt + voff);
    }
    __syncthreads();

    // scores: S = (QK^T)*0.125 + sig2*exp(-dist2*inv2l2)
    f4 S[2][4];
    #pragma unroll
    for (int fm=0; fm<4; fm++){
      bf8 xmh, xml;
      if (l4 < 2){
        size_t off = (size_t)(b*NSEQ + mt + fm*16 + l15)*16 + l4*8;
        xmh = *(const bf8*)(xhi + off);
        xml = *(const bf8*)(xlo + off);
      } else {
        #pragma unroll
        for (int j=0;j<8;j++){ xmh[j] = (__bf16)0.f; xml[j] = (__bf16)0.f; }
      }
      float x2m = x2g[b*NSEQ + mt + fm*16 + l15];
      #pragma unroll
      for (int fq=0; fq<2; fq++){
        f4 s, xd;
        #pragma unroll
        for (int r=0;r<4;r++){ s[r]=0.f; xd[r]=0.f; }
        #pragma unroll
        for (int ks=0; ks<2; ks++){
          int mrow = fm*16 + l15;
          int ck = (ks*4 + l4) ^ (mrow & 7);
          bf8 kbh = *(const bf8*)&sKhi[mrow*64 + ck*8];
          bf8 kbl = *(const bf8*)&sKlo[mrow*64 + ck*8];
          s = mfma_bf(qh[fq][ks], kbh, s);
          s = mfma_bf(qh[fq][ks], kbl, s);
          s = mfma_bf(ql[fq][ks], kbh, s);
        }
        xd = mfma_bf(xqh[fq], xmh, xd);
        xd = mfma_bf(xqh[fq], xml, xd);
        xd = mfma_bf(xql[fq], xmh, xd);
        #pragma unroll
        for (int r=0;r<4;r++){
          float d2 = fmaxf(x2q[fq][r] + x2m - 2.f*xd[r], 0.f);
          S[fq][fm][r] = s[r]*0.125f + sig2*__expf(-d2*inv2l2);
        }
      }
    }

    // online softmax (row stats per q-row; reduce over 4 fm frags + 16 lanes)
    #pragma unroll
    for (int fq=0; fq<2; fq++){
      f4 tm;
      #pragma unroll
      for (int r=0;r<4;r++)
        tm[r] = fmaxf(fmaxf(S[fq][0][r], S[fq][1][r]), fmaxf(S[fq][2][r], S[fq][3][r]));
      #pragma unroll
      for (int mask=1; mask<16; mask<<=1)
        #pragma unroll
        for (int r=0;r<4;r++) tm[r] = fmaxf(tm[r], __shfl_xor(tm[r], mask));
      f4 mnew, sc;
      #pragma unroll
      for (int r=0;r<4;r++){
        mnew[r] = fmaxf(mrun[fq][r], tm[r]);
        sc[r]   = __expf(mrun[fq][r] - mnew[r]);
      }
      mrun[fq] = mnew;
      f4 ps;
      #pragma unroll
      for (int r=0;r<4;r++) ps[r] = 0.f;
      #pragma unroll
      for (int fm=0; fm<4; fm++)
        #pragma unroll
        for (int r=0;r<4;r++){
          float p = __expf(S[fq][fm][r] - mnew[r]);
          S[fq][fm][r] = p;
          ps[r] += p;
        }
      #pragma unroll
      for (int mask=1; mask<16; mask<<=1)
        #pragma unroll
        for (int r=0;r<4;r++) ps[r] += __shfl_xor(ps[r], mask);
      #pragma unroll
      for (int r=0;r<4;r++) lrun[fq][r] = lrun[fq][r]*sc[r] + ps[r];
      #pragma unroll
      for (int fd=0; fd<4; fd++)
        #pragma unroll
        for (int r=0;r<4;r++){
          ctx[fq][fd][r] *= sc[r];
          var[fq][fd][r] *= sc[r]*sc[r];
        }
      // write p (f16) to swizzled LDS P tile (wave-private rows; no barrier needed)
      #pragma unroll
      for (int fm=0; fm<4; fm++)
        #pragma unroll
        for (int r=0;r<4;r++){
          int qrow = wq + fq*16 + l4*4 + r;
          int m    = fm*16 + l15;
          int ck   = (m>>3) ^ (qrow & 7);
          sP[qrow*64 + ck*8 + (m&7)] = (_Float16)S[fq][fm][r];
        }
    }

    // PV: ctx += P @ V^T-tile, var += P^2 @ Vv (f16 MFMA)
    #pragma unroll
    for (int ks=0; ks<2; ks++){
      h8 pa[2], pa2[2];
      #pragma unroll
      for (int fq=0; fq<2; fq++){
        int qrow = wq + fq*16 + l15;
        int ck = (ks*4 + l4) ^ (qrow & 7);
        pa[fq] = *(const h8*)&sP[qrow*64 + ck*8];
        #pragma unroll
        for (int j=0;j<8;j++){
          float pv = (float)pa[fq][j];
          pa2[fq][j] = (_Float16)(pv*pv);
        }
      }
      #pragma unroll
      for (int fd=0; fd<4; fd++){
        int drow = fd*16 + l15;
        int ck = (ks*4 + l4) ^ (drow & 7);
        h8 vb  = *(const h8*)&sVt[drow*64 + ck*8];
        h8 vvb = *(const h8*)&sVvt[drow*64 + ck*8];
        #pragma unroll
        for (int fq=0; fq<2; fq++){
          ctx[fq][fd] = mfma_h(pa[fq],  vb,  ctx[fq][fd]);
          var[fq][fd] = mfma_h(pa2[fq], vvb, var[fq][fd]);
        }
      }
    }
  }

  // epilogue: normalize and store
  #pragma unroll
  for (int fq=0; fq<2; fq++)
    #pragma unroll
    for (int fd=0; fd<4; fd++){
      int col = h*DK + fd*16 + l15;
      #pragma unroll
      for (int r=0;r<4;r++){
        int t = t0 + wq + fq*16 + l4*4 + r;
        float linv = 1.f / lrun[fq][r];
        size_t idx = (size_t)t*D_MODEL + col;
        ctx_out[idx] = ctx[fq][fd][r] * linv;
        var_out[idx] = var[fq][fd][r] * linv * linv;
      }
    }
}

// ---------------- host launch ----------------

extern "C" void kernel_launch(void* const* d_in, const int* in_sizes, int n_in,
                              void* d_out, int out_size, void* d_ws, size_t ws_size,
                              hipStream_t stream){
  (void)in_sizes; (void)n_in; (void)out_size; (void)ws_size;
  const float* H      = (const float*)d_in[0];
  const float* x_raw  = (const float*)d_in[1];
  const float* Wq_mu  = (const float*)d_in[2];
  const float* bq_mu  = (const float*)d_in[4];
  const float* Wk_mu  = (const float*)d_in[6];
  const float* bk_mu  = (const float*)d_in[8];
  const float* Wv_mu  = (const float*)d_in[10];
  const float* Wv_rho = (const float*)d_in[11];
  const float* bv_mu  = (const float*)d_in[12];
  const float* bv_rho = (const float*)d_in[13];
  const float* Wo_mu  = (const float*)d_in[14];
  const float* Wo_rho = (const float*)d_in[15];
  const float* bo_mu  = (const float*)d_in[16];
  const float* bo_rho = (const float*)d_in[17];
  const float* lsf    = (const float*)d_in[18];
  const float* lln    = (const float*)d_in[19];

  char* ws = (char*)d_ws;
  const size_t MB = 1024*1024;
  // ws layout (peak ~197 MB)
  __bf16* Hhi    = (__bf16*)(ws + 0*MB);     // 16MB
  __bf16* Hlo    = (__bf16*)(ws + 16*MB);    // 16MB
  __bf16* H2b    = (__bf16*)(ws + 32*MB);    // 16MB
  __bf16* Wqhi   = (__bf16*)(ws + 48*MB);
  __bf16* Wqlo   = (__bf16*)(ws + 50*MB);
  __bf16* Wkhi   = (__bf16*)(ws + 52*MB);
  __bf16* Wklo   = (__bf16*)(ws + 54*MB);
  __bf16* Wvhi   = (__bf16*)(ws + 56*MB);
  __bf16* Wvlo   = (__bf16*)(ws + 58*MB);
  __bf16* Wvsig2 = (__bf16*)(ws + 60*MB);
  __bf16* Wohi   = (__bf16*)(ws + 62*MB);
  __bf16* Wolo   = (__bf16*)(ws + 64*MB);
  __bf16* Wosig2 = (__bf16*)(ws + 66*MB);
  __bf16* Qhi    = (__bf16*)(ws + 68*MB);
  __bf16* Qlo    = (__bf16*)(ws + 84*MB);
  __bf16* Khi    = (__bf16*)(ws + 100*MB);
  __bf16* Klo    = (__bf16*)(ws + 116*MB);
  _Float16* Vt   = (_Float16*)(ws + 132*MB); // transposed [b, o, n]
  _Float16* Vvt  = (_Float16*)(ws + 148*MB);
  float*  ctx    = (float*)(ws + 164*MB);    // 32MB f32
  __bf16* xhi    = (__bf16*)(ws + 196*MB);
  __bf16* xlo    = (__bf16*)(ws + 196*MB + 256*1024);
  float*  x2     = (float*)(ws + 196*MB + 512*1024);
  // reuse (H dead after projections)
  __bf16* ctxhi = Hhi; __bf16* ctxlo = Hlo; __bf16* ctx2b = H2b;

  float* out_mean = (float*)d_out;
  float* out_var  = out_mean + (size_t)TOK*D_MODEL;

  const int TD = TOK*D_MODEL;    // 8388608
  const int DD = D_MODEL*D_MODEL;

  // prep
  split_f32_bf16<<<TD/1024, 256, 0, stream>>>(H, Hhi, Hlo, TD);
  sq_to_bf16    <<<TD/1024, 256, 0, stream>>>(H, H2b, TD, 0);
  split_f32_bf16<<<DD/1024, 256, 0, stream>>>(Wq_mu, Wqhi, Wqlo, DD);
  split_f32_bf16<<<DD/1024, 256, 0, stream>>>(Wk_mu, Wkhi, Wklo, DD);
  split_f32_bf16<<<DD/1024, 256, 0, stream>>>(Wv_mu, Wvhi, Wvlo, DD);
  split_f32_bf16<<<DD/1024, 256, 0, stream>>>(Wo_mu, Wohi, Wolo, DD);
  sq_to_bf16    <<<DD/1024, 256, 0, stream>>>(Wv_rho, Wvsig2, DD, 1);
  sq_to_bf16    <<<DD/1024, 256, 0, stream>>>(Wo_rho, Wosig2, DD, 1);
  split_f32_bf16<<<(TOK*16)/1024, 256, 0, stream>>>(x_raw, xhi, xlo, TOK*16);
  x2_kernel     <<<TOK/256, 256, 0, stream>>>(x_raw, x2, TOK);

  // projections (M=8192, N=1024, K=1024; grid 64*8)
  gemm_bt<true><<<512, 256, 0, stream>>>(Hhi, Hlo, Wqhi, Wqlo, TOK, D_MODEL, D_MODEL,
      bq_mu, 0, nullptr, nullptr, Qhi, Qlo, nullptr);
  gemm_bt<true><<<512, 256, 0, stream>>>(Hhi, Hlo, Wkhi, Wklo, TOK, D_MODEL, D_MODEL,
      bk_mu, 0, nullptr, nullptr, Khi, Klo, nullptr);
  gemm_bt<true><<<512, 256, 0, stream>>>(Hhi, Hlo, Wvhi, Wvlo, TOK, D_MODEL, D_MODEL,
      bv_mu, 0, nullptr, nullptr, nullptr, nullptr, Vt);
  gemm_bt<false><<<512, 256, 0, stream>>>(H2b, nullptr, Wvsig2, nullptr, TOK, D_MODEL, D_MODEL,
      bv_rho, 1, nullptr, nullptr, nullptr, nullptr, Vvt);

  // attention (writes ctx f32 and var_attn directly into out_var)
  attn_kernel<<<1024, 256, 0, stream>>>(Qhi, Qlo, Khi, Klo, Vt, Vvt,
      xhi, xlo, x2, lsf, lln, ctx, out_var);

  // output projections
  split_f32_bf16<<<TD/1024, 256, 0, stream>>>(ctx, ctxhi, ctxlo, TD);
  sq_to_bf16    <<<TD/1024, 256, 0, stream>>>(ctx, ctx2b, TD, 0);
  gemm_bt<true><<<512, 256, 0, stream>>>(ctxhi, ctxlo, Wohi, Wolo, TOK, D_MODEL, D_MODEL,
      bo_mu, 0, nullptr, out_mean, nullptr, nullptr, nullptr);
  gemm_bt<false><<<512, 256, 0, stream>>>(ctx2b, nullptr, Wosig2, nullptr, TOK, D_MODEL, D_MODEL,
      bo_rho, 1, out_var, out_var, nullptr, nullptr, nullptr);
}

// Round 2
// 479.454 us; speedup vs baseline: 1.9009x; 1.9009x over previous
//
#include <hip/hip_runtime.h>
#include <hip/hip_bf16.h>
#include <stdint.h>

// Bayesian MHA forward for MI355X (round 2).
// Precision plan: out_mean projection = split-bf16 (3-MFMA, ~fp32).
// Everything else rides softmax damping: Q/K/V/Vv GEMMs plain bf16,
// attention QK^T + RBF cross-term in f16 single-MFMA, PV f16.

#define D_MODEL 1024
#define NSEQ    1024
#define BATCH   8
#define NHEADS  16
#define DK      64
#define TOK     8192   // BATCH*NSEQ

typedef __bf16    bf8 __attribute__((ext_vector_type(8)));
typedef _Float16  h8  __attribute__((ext_vector_type(8)));
typedef float     f4  __attribute__((ext_vector_type(4)));

__device__ __forceinline__ f4 mfma_bf(bf8 a, bf8 b, f4 c){
  return __builtin_amdgcn_mfma_f32_16x16x32_bf16(a, b, c, 0, 0, 0);
}
__device__ __forceinline__ f4 mfma_h(h8 a, h8 b, f4 c){
  return __builtin_amdgcn_mfma_f32_16x16x32_f16(a, b, c, 0, 0, 0);
}

// global -> LDS async copy, 16B per lane. LDS dest must be (uniform base + lane*16).
__device__ __forceinline__ void async_copy16(void* lds, const void* g){
  __builtin_amdgcn_global_load_lds(
      (const __attribute__((address_space(1))) unsigned int*)(uintptr_t)g,
      (__attribute__((address_space(3))) unsigned int*)(unsigned int)(uintptr_t)lds,
      16, 0, 0);
}

__device__ __forceinline__ float softplusf(float x){
  return (x > 20.f) ? x : log1pf(__expf(x));
}

// ---------------- prep kernels ----------------

// Hb = bf16(H), H2b = bf16(H*H)
__global__ __launch_bounds__(256) void prep_H(
    const float* __restrict__ in, __bf16* __restrict__ b, __bf16* __restrict__ sq, int n){
  int i = (blockIdx.x*256 + threadIdx.x)*4;
  if (i >= n) return;
  float4 v = *(const float4*)(in + i);
  float vv[4] = {v.x, v.y, v.z, v.w};
  #pragma unroll
  for (int j=0;j<4;j++){
    b[i+j]  = (__bf16)vv[j];
    sq[i+j] = (__bf16)(vv[j]*vv[j]);
  }
}

__global__ __launch_bounds__(256) void cast_bf16_k(
    const float* __restrict__ in, __bf16* __restrict__ out, int n){
  int i = (blockIdx.x*256 + threadIdx.x)*4;
  if (i >= n) return;
  float4 v = *(const float4*)(in + i);
  float vv[4] = {v.x, v.y, v.z, v.w};
  #pragma unroll
  for (int j=0;j<4;j++) out[i+j] = (__bf16)vv[j];
}

// out = bf16(softplus(x)^2)
__global__ __launch_bounds__(256) void sp2_bf16(
    const float* __restrict__ in, __bf16* __restrict__ out, int n){
  int i = (blockIdx.x*256 + threadIdx.x)*4;
  if (i >= n) return;
  float4 v = *(const float4*)(in + i);
  float vv[4] = {v.x, v.y, v.z, v.w};
  #pragma unroll
  for (int j=0;j<4;j++){ float s = softplusf(vv[j]); out[i+j] = (__bf16)(s*s); }
}

// f32 -> bf16 hi/lo split
__global__ __launch_bounds__(256) void split_f32_bf16(
    const float* __restrict__ in, __bf16* __restrict__ hi, __bf16* __restrict__ lo, int n){
  int i = (blockIdx.x*256 + threadIdx.x)*4;
  if (i >= n) return;
  float4 v = *(const float4*)(in + i);
  float vv[4] = {v.x, v.y, v.z, v.w};
  #pragma unroll
  for (int j=0;j<4;j++){
    __bf16 h = (__bf16)vv[j];
    hi[i+j] = h;
    lo[i+j] = (__bf16)(vv[j] - (float)h);
  }
}

// ctx -> hi/lo split + bf16(ctx^2)
__global__ __launch_bounds__(256) void prep_ctx(
    const float* __restrict__ in, __bf16* __restrict__ hi, __bf16* __restrict__ lo,
    __bf16* __restrict__ sq, int n){
  int i = (blockIdx.x*256 + threadIdx.x)*4;
  if (i >= n) return;
  float4 v = *(const float4*)(in + i);
  float vv[4] = {v.x, v.y, v.z, v.w};
  #pragma unroll
  for (int j=0;j<4;j++){
    float f = vv[j];
    __bf16 h = (__bf16)f;
    hi[i+j] = h;
    lo[i+j] = (__bf16)(f - (float)h);
    sq[i+j] = (__bf16)(f*f);
  }
}

// xh = f16(x_raw), x2[t] = sum_j x[t][j]^2
__global__ __launch_bounds__(256) void prep_x(
    const float* __restrict__ x, _Float16* __restrict__ xh, float* __restrict__ x2, int T){
  int t = blockIdx.x*256 + threadIdx.x;
  if (t >= T) return;
  const float* p = x + (size_t)t*16;
  float s = 0.f;
  #pragma unroll
  for (int j=0;j<16;j++){
    float f = p[j];
    xh[(size_t)t*16 + j] = (_Float16)f;
    s += f*f;
  }
  x2[t] = s;
}

// ---------------- GEMM: C = A @ B^T (+bias), A:[M,K], B:[N,K] both K-contiguous ----------------
// 128x128 tile, BK=32, 4 waves (2x2, each 64x64). LDS chunks XOR-swizzled (2-bit).
// SPLIT: hi/lo pairs, 3 MFMAs per fragment pair (~fp32 accuracy).
// Outputs: outF f32, outH f16 [row][col], outT transposed f16 [b, col, row&1023].
template<bool SPLIT>
__global__ __launch_bounds__(256) void gemm_bt(
    const __bf16* __restrict__ Ahi, const __bf16* __restrict__ Alo,
    const __bf16* __restrict__ Bhi, const __bf16* __restrict__ Blo,
    int M, int N, int K,
    const float* __restrict__ bias, int bias_sp2,
    const float* __restrict__ addend,
    float* __restrict__ outF,
    _Float16* __restrict__ outH,
    _Float16* __restrict__ outT)
{
  __shared__ __bf16 sA[(SPLIT?2:1)*128*32];
  __shared__ __bf16 sB[(SPLIT?2:1)*128*32];
  const int tid = threadIdx.x;
  const int lane = tid & 63;
  const int wid  = tid >> 6;
  const int wm = wid >> 1, wn = wid & 1;
  const int l15 = lane & 15, l4 = lane >> 4;
  const int nbn = N >> 7;
  // XCD-aware bijective swizzle (grid is always a multiple of 8 here)
  const int nwg = gridDim.x;
  const int bid = blockIdx.x;
  const int swz = (bid & 7) * (nwg >> 3) + (bid >> 3);
  const int bm = swz / nbn, bn = swz % nbn;
  const int row0 = bm << 7, col0 = bn << 7;

  f4 acc[4][4];
  #pragma unroll
  for (int i=0;i<4;i++)
    #pragma unroll
    for (int j=0;j<4;j++)
      #pragma unroll
      for (int r=0;r<4;r++) acc[i][j][r] = 0.f;

  const int c0 = tid, c1 = tid + 256;
  const int r0 = c0 >> 2, ch0 = c0 & 3;
  const int r1 = c1 >> 2, ch1 = c1 & 3;
  const int k0off = ((ch0 ^ (r0 & 3)) << 3);
  const int k1off = ((ch1 ^ (r1 & 3)) << 3);

  for (int kt = 0; kt < K; kt += 32){
    __syncthreads();
    async_copy16(&sA[c0*8], Ahi + (size_t)(row0+r0)*K + kt + k0off);
    async_copy16(&sA[c1*8], Ahi + (size_t)(row0+r1)*K + kt + k1off);
    async_copy16(&sB[c0*8], Bhi + (size_t)(col0+r0)*K + kt + k0off);
    async_copy16(&sB[c1*8], Bhi + (size_t)(col0+r1)*K + kt + k1off);
    if (SPLIT){
      async_copy16(&sA[4096 + c0*8], Alo + (size_t)(row0+r0)*K + kt + k0off);
      async_copy16(&sA[4096 + c1*8], Alo + (size_t)(row0+r1)*K + kt + k1off);
      async_copy16(&sB[4096 + c0*8], Blo + (size_t)(col0+r0)*K + kt + k0off);
      async_copy16(&sB[4096 + c1*8], Blo + (size_t)(col0+r1)*K + kt + k1off);
    }
    __syncthreads();

    bf8 a0[4], a1[4], b0[4], b1[4];
    #pragma unroll
    for (int mf=0; mf<4; mf++){
      int r  = (wm<<6) + (mf<<4) + l15;
      int ck = l4 ^ (r & 3);
      a0[mf] = *(const bf8*)&sA[r*32 + ck*8];
      if (SPLIT) a1[mf] = *(const bf8*)&sA[4096 + r*32 + ck*8];
    }
    #pragma unroll
    for (int nf=0; nf<4; nf++){
      int r  = (wn<<6) + (nf<<4) + l15;
      int ck = l4 ^ (r & 3);
      b0[nf] = *(const bf8*)&sB[r*32 + ck*8];
      if (SPLIT) b1[nf] = *(const bf8*)&sB[4096 + r*32 + ck*8];
    }
    #pragma unroll
    for (int mf=0; mf<4; mf++)
      #pragma unroll
      for (int nf=0; nf<4; nf++){
        acc[mf][nf] = mfma_bf(a0[mf], b0[nf], acc[mf][nf]);
        if (SPLIT){
          acc[mf][nf] = mfma_bf(a0[mf], b1[nf], acc[mf][nf]);
          acc[mf][nf] = mfma_bf(a1[mf], b0[nf], acc[mf][nf]);
        }
      }
  }

  #pragma unroll
  for (int nf=0; nf<4; nf++){
    int col = col0 + (wn<<6) + (nf<<4) + l15;
    float bv = 0.f;
    if (bias){
      float bb = bias[col];
      if (bias_sp2){ float s = softplusf(bb); bv = s*s; } else bv = bb;
    }
    #pragma unroll
    for (int mf=0; mf<4; mf++){
      int rbase = row0 + (wm<<6) + (mf<<4) + (l4<<2);
      #pragma unroll
      for (int r=0;r<4;r++){
        int row = rbase + r;
        size_t idx = (size_t)row*N + col;
        float v = acc[mf][nf][r] + bv;
        if (addend) v += addend[idx];
        if (outF) outF[idx] = v;
        if (outH) outH[idx] = (_Float16)v;
        if (outT) outT[((size_t)(row>>10)<<20) + ((size_t)col<<10) + (row & 1023)] = (_Float16)v;
      }
    }
  }
}

// ---------------- fused attention (flash-style, + RBF scores) ----------------
// grid: 1024 blocks = 8 q-tiles x (B*H). 256 thr = 4 waves, each wave owns 32 q-rows.
// Double-buffered KV staging; f16 QK^T + RBF; row-sum via ones-MFMA; defer-max.
__global__ __launch_bounds__(256, 2) void attn_kernel(
    const _Float16* __restrict__ Qh, const _Float16* __restrict__ Kh,
    const _Float16* __restrict__ Vt, const _Float16* __restrict__ Vvt,
    const _Float16* __restrict__ xh, const float* __restrict__ x2g,
    const float* __restrict__ log_sigma_f, const float* __restrict__ log_length,
    float* __restrict__ ctx_out, float* __restrict__ var_out)
{
  // XCD swizzle: 8 qt-blocks of the same (b,h) land on the same XCD -> K/V L2 reuse
  const int bid = blockIdx.x;
  const int swz = (bid & 7) * 128 + (bid >> 3);
  const int qt = swz & 7;
  const int bh = swz >> 3;
  const int b  = bh >> 4, h = bh & 15;
  const int tid = threadIdx.x;
  const int lane = tid & 63, wid = tid >> 6;
  const int l15 = lane & 15, l4 = lane >> 4;
  const float sig2   = __expf(2.f*log_sigma_f[h]);
  const float inv2l2 = 0.5f*__expf(-2.f*log_length[h]);

  __shared__ _Float16 sK[2][4096];   // [m][d] 64x64, XOR-swizzled
  __shared__ _Float16 sV[2][4096];   // [d][m]
  __shared__ _Float16 sVv[2][4096];  // [d][m]
  __shared__ _Float16 sx[2][1024];   // [m][16]
  __shared__ float    sx2[2][64];
  __shared__ _Float16 sP[8192];      // [q][m] 128x64, swizzled, wave-private rows

  const int t0 = b*NSEQ + qt*128;
  const int wq = wid*32;

  // Q fragments (f16), held in regs for the whole block
  h8 qf[2][2];
  #pragma unroll
  for (int fq=0; fq<2; fq++)
    #pragma unroll
    for (int ks=0; ks<2; ks++){
      size_t off = (size_t)(t0 + wq + fq*16 + l15)*D_MODEL + h*DK + ks*32 + l4*8;
      qf[fq][ks] = *(const h8*)(Qh + off);
    }
  // x_raw q fragments (K=16 zero-padded to 32)
  h8 xq[2];
  #pragma unroll
  for (int fq=0; fq<2; fq++){
    #pragma unroll
    for (int j=0;j<8;j++) xq[fq][j] = (_Float16)0.f;
    if (l4 < 2){
      size_t off = (size_t)(t0 + wq + fq*16 + l15)*16 + l4*8;
      xq[fq] = *(const h8*)(xh + off);
    }
  }
  float x2q[2][4];
  #pragma unroll
  for (int fq=0; fq<2; fq++)
    #pragma unroll
    for (int r=0;r<4;r++) x2q[fq][r] = x2g[t0 + wq + fq*16 + l4*4 + r];

  h8 ones;
  #pragma unroll
  for (int j=0;j<8;j++) ones[j] = (_Float16)1.f;

  f4 mrun[2], lacc[2], ctx[2][4], var[2][4];
  #pragma unroll
  for (int fq=0; fq<2; fq++){
    #pragma unroll
    for (int r=0;r<4;r++){ mrun[fq][r] = -1e30f; lacc[fq][r] = 0.f; }
    #pragma unroll
    for (int fd=0; fd<4; fd++)
      #pragma unroll
      for (int r=0;r<4;r++){ ctx[fq][fd][r] = 0.f; var[fq][fd][r] = 0.f; }
  }

  // staging: 1680 chunks of 16B (K 512, V 512, Vv 512, x 128, x2 16)
  auto stage = [&](int bi, int mt){
    for (int c = tid; c < 1680; c += 256){
      if (c < 512){
        int rg = c >> 3, sw = (((c & 7) ^ (rg & 7)) << 3);
        async_copy16(&sK[bi][c*8], Kh + (size_t)(b*NSEQ + mt + rg)*D_MODEL + h*DK + sw);
      } else if (c < 1024){
        int cc = c - 512; int rg = cc >> 3, sw = (((cc & 7) ^ (rg & 7)) << 3);
        async_copy16(&sV[bi][cc*8], Vt + ((size_t)b << 20) + (size_t)(h*DK + rg)*NSEQ + mt + sw);
      } else if (c < 1536){
        int cc = c - 1024; int rg = cc >> 3, sw = (((cc & 7) ^ (rg & 7)) << 3);
        async_copy16(&sVv[bi][cc*8], Vvt + ((size_t)b << 20) + (size_t)(h*DK + rg)*NSEQ + mt + sw);
      } else if (c < 1664){
        int cc = c - 1536;
        async_copy16(&sx[bi][cc*8], xh + (size_t)(b*NSEQ + mt)*16 + cc*8);
      } else {
        int cc = c - 1664;
        async_copy16(&sx2[bi][cc*4], x2g + b*NSEQ + mt + cc*4);
      }
    }
  };

  stage(0, 0);
  __syncthreads();

  for (int it = 0; it < NSEQ/64; it++){
    const int bi = it & 1;
    if (it + 1 < NSEQ/64) stage(bi^1, (it+1)*64);

    // scores: S = (QK^T)*0.125 + sig2*exp(-dist2*inv2l2)
    f4 S[2][4];
    #pragma unroll
    for (int fm=0; fm<4; fm++){
      int mrow = fm*16 + l15;
      h8 xb;
      #pragma unroll
      for (int j=0;j<8;j++) xb[j] = (_Float16)0.f;
      if (l4 < 2) xb = *(const h8*)&sx[bi][mrow*16 + l4*8];
      float x2m = sx2[bi][mrow];
      #pragma unroll
      for (int fq=0; fq<2; fq++){
        f4 s, xd;
        #pragma unroll
        for (int r=0;r<4;r++){ s[r]=0.f; xd[r]=0.f; }
        #pragma unroll
        for (int ks=0; ks<2; ks++){
          int ck = (ks*4 + l4) ^ (mrow & 7);
          h8 kb = *(const h8*)&sK[bi][mrow*64 + ck*8];
          s = mfma_h(qf[fq][ks], kb, s);
        }
        xd = mfma_h(xq[fq], xb, xd);
        #pragma unroll
        for (int r=0;r<4;r++){
          float d2 = fmaxf(x2q[fq][r] + x2m - 2.f*xd[r], 0.f);
          S[fq][fm][r] = s[r]*0.125f + sig2*__expf(-d2*inv2l2);
        }
      }
    }

    // online softmax with deferred max (thr=4; P <= e^4, P^2 <= e^8 fits f16)
    #pragma unroll
    for (int fq=0; fq<2; fq++){
      f4 tm;
      #pragma unroll
      for (int r=0;r<4;r++)
        tm[r] = fmaxf(fmaxf(S[fq][0][r], S[fq][1][r]), fmaxf(S[fq][2][r], S[fq][3][r]));
      #pragma unroll
      for (int mask=1; mask<16; mask<<=1)
        #pragma unroll
        for (int r=0;r<4;r++) tm[r] = fmaxf(tm[r], __shfl_xor(tm[r], mask));
      int nd = 0;
      #pragma unroll
      for (int r=0;r<4;r++) nd |= (tm[r] > mrun[fq][r] + 4.f) ? 1 : 0;
      if (__any(nd)){
        f4 sc;
        #pragma unroll
        for (int r=0;r<4;r++){
          float mn = fmaxf(mrun[fq][r], tm[r]);
          sc[r] = __expf(mrun[fq][r] - mn);
          mrun[fq][r] = mn;
          lacc[fq][r] *= sc[r];
        }
        #pragma unroll
        for (int fd=0; fd<4; fd++)
          #pragma unroll
          for (int r=0;r<4;r++){
            ctx[fq][fd][r] *= sc[r];
            var[fq][fd][r] *= sc[r]*sc[r];
          }
      }
      #pragma unroll
      for (int fm=0; fm<4; fm++)
        #pragma unroll
        for (int r=0;r<4;r++){
          float p = __expf(S[fq][fm][r] - mrun[fq][r]);
          int qrow = wq + fq*16 + l4*4 + r;
          int m    = fm*16 + l15;
          int ck   = (m>>3) ^ (qrow & 7);
          sP[qrow*64 + ck*8 + (m&7)] = (_Float16)p;
        }
    }

    // PV: ctx += P @ V, var += P^2 @ Vv, l += P @ 1 (f16 MFMA)
    #pragma unroll
    for (int ks=0; ks<2; ks++){
      h8 pa[2], pa2[2];
      #pragma unroll
      for (int fq=0; fq<2; fq++){
        int qrow = wq + fq*16 + l15;
        int ck = (ks*4 + l4) ^ (qrow & 7);
        pa[fq] = *(const h8*)&sP[qrow*64 + ck*8];
        pa2[fq] = pa[fq]*pa[fq];
        lacc[fq] = mfma_h(pa[fq], ones, lacc[fq]);
      }
      #pragma unroll
      for (int fd=0; fd<4; fd++){
        int drow = fd*16 + l15;
        int ck = (ks*4 + l4) ^ (drow & 7);
        h8 vb  = *(const h8*)&sV[bi][drow*64 + ck*8];
        h8 vvb = *(const h8*)&sVv[bi][drow*64 + ck*8];
        #pragma unroll
        for (int fq=0; fq<2; fq++){
          ctx[fq][fd] = mfma_h(pa[fq],  vb,  ctx[fq][fd]);
          var[fq][fd] = mfma_h(pa2[fq], vvb, var[fq][fd]);
        }
      }
    }
    __syncthreads();
  }

  // epilogue: normalize and store
  #pragma unroll
  for (int fq=0; fq<2; fq++)
    #pragma unroll
    for (int fd=0; fd<4; fd++){
      int col = h*DK + fd*16 + l15;
      #pragma unroll
      for (int r=0;r<4;r++){
        int t = t0 + wq + fq*16 + l4*4 + r;
        float linv = 1.f / lacc[fq][r];
        size_t idx = (size_t)t*D_MODEL + col;
        ctx_out[idx] = ctx[fq][fd][r] * linv;
        var_out[idx] = var[fq][fd][r] * linv * linv;
      }
    }
}

// ---------------- host launch ----------------

extern "C" void kernel_launch(void* const* d_in, const int* in_sizes, int n_in,
                              void* d_out, int out_size, void* d_ws, size_t ws_size,
                              hipStream_t stream){
  (void)in_sizes; (void)n_in; (void)out_size; (void)ws_size;
  const float* H      = (const float*)d_in[0];
  const float* x_raw  = (const float*)d_in[1];
  const float* Wq_mu  = (const float*)d_in[2];
  const float* bq_mu  = (const float*)d_in[4];
  const float* Wk_mu  = (const float*)d_in[6];
  const float* bk_mu  = (const float*)d_in[8];
  const float* Wv_mu  = (const float*)d_in[10];
  const float* Wv_rho = (const float*)d_in[11];
  const float* bv_mu  = (const float*)d_in[12];
  const float* bv_rho = (const float*)d_in[13];
  const float* Wo_mu  = (const float*)d_in[14];
  const float* Wo_rho = (const float*)d_in[15];
  const float* bo_mu  = (const float*)d_in[16];
  const float* bo_rho = (const float*)d_in[17];
  const float* lsf    = (const float*)d_in[18];
  const float* lln    = (const float*)d_in[19];

  char* ws = (char*)d_ws;
  const size_t MB = 1024*1024;
  __bf16* Hb     = (__bf16*)(ws + 0*MB);     // 16MB
  __bf16* H2b    = (__bf16*)(ws + 16*MB);    // 16MB
  __bf16* Wqb    = (__bf16*)(ws + 32*MB);
  __bf16* Wkb    = (__bf16*)(ws + 34*MB);
  __bf16* Wvb    = (__bf16*)(ws + 36*MB);
  __bf16* Wvs2   = (__bf16*)(ws + 38*MB);
  __bf16* Wohi   = (__bf16*)(ws + 40*MB);
  __bf16* Wolo   = (__bf16*)(ws + 42*MB);
  __bf16* Wos2   = (__bf16*)(ws + 44*MB);
  _Float16* Qh   = (_Float16*)(ws + 46*MB);  // 16MB
  _Float16* Kh   = (_Float16*)(ws + 62*MB);  // 16MB
  _Float16* Vt   = (_Float16*)(ws + 78*MB);  // 16MB, transposed [b, o, n]
  _Float16* Vvt  = (_Float16*)(ws + 94*MB);  // 16MB
  float*  ctx    = (float*)(ws + 110*MB);    // 32MB
  _Float16* xh   = (_Float16*)(ws + 142*MB); // 256KB
  float*  x2     = (float*)(ws + 142*MB + 256*1024);
  // reuse dead buffers for ctx preprocessing
  __bf16* ctxhi = (__bf16*)(ws + 0*MB);      // Hb dead
  __bf16* ctxlo = (__bf16*)(ws + 16*MB);     // H2b dead
  __bf16* ctx2b = (__bf16*)(ws + 46*MB);     // Qh dead after attn

  float* out_mean = (float*)d_out;
  float* out_var  = out_mean + (size_t)TOK*D_MODEL;

  const int TD = TOK*D_MODEL;
  const int DD = D_MODEL*D_MODEL;

  // prep
  prep_H    <<<TD/1024, 256, 0, stream>>>(H, Hb, H2b, TD);
  cast_bf16_k<<<DD/1024, 256, 0, stream>>>(Wq_mu, Wqb, DD);
  cast_bf16_k<<<DD/1024, 256, 0, stream>>>(Wk_mu, Wkb, DD);
  cast_bf16_k<<<DD/1024, 256, 0, stream>>>(Wv_mu, Wvb, DD);
  sp2_bf16  <<<DD/1024, 256, 0, stream>>>(Wv_rho, Wvs2, DD);
  split_f32_bf16<<<DD/1024, 256, 0, stream>>>(Wo_mu, Wohi, Wolo, DD);
  sp2_bf16  <<<DD/1024, 256, 0, stream>>>(Wo_rho, Wos2, DD);
  prep_x    <<<TOK/256, 256, 0, stream>>>(x_raw, xh, x2, TOK);

  // projections (M=8192, N=1024, K=1024; grid 512) -- plain bf16
  gemm_bt<false><<<512, 256, 0, stream>>>(Hb, nullptr, Wqb, nullptr, TOK, D_MODEL, D_MODEL,
      bq_mu, 0, nullptr, nullptr, Qh, nullptr);
  gemm_bt<false><<<512, 256, 0, stream>>>(Hb, nullptr, Wkb, nullptr, TOK, D_MODEL, D_MODEL,
      bk_mu, 0, nullptr, nullptr, Kh, nullptr);
  gemm_bt<false><<<512, 256, 0, stream>>>(Hb, nullptr, Wvb, nullptr, TOK, D_MODEL, D_MODEL,
      bv_mu, 0, nullptr, nullptr, nullptr, Vt);
  gemm_bt<false><<<512, 256, 0, stream>>>(H2b, nullptr, Wvs2, nullptr, TOK, D_MODEL, D_MODEL,
      bv_rho, 1, nullptr, nullptr, nullptr, Vvt);

  // attention (writes ctx f32 and var_attn directly into out_var)
  attn_kernel<<<1024, 256, 0, stream>>>(Qh, Kh, Vt, Vvt, xh, x2, lsf, lln, ctx, out_var);

  // output projections
  prep_ctx<<<TD/1024, 256, 0, stream>>>(ctx, ctxhi, ctxlo, ctx2b, TD);
  gemm_bt<true><<<512, 256, 0, stream>>>(ctxhi, ctxlo, Wohi, Wolo, TOK, D_MODEL, D_MODEL,
      bo_mu, 0, nullptr, out_mean, nullptr, nullptr);
  gemm_bt<false><<<512, 256, 0, stream>>>(ctx2b, nullptr, Wos2, nullptr, TOK, D_MODEL, D_MODEL,
      bo_rho, 1, out_var, out_var, nullptr, nullptr);
}